// Round 2
// baseline (269.506 us; speedup 1.0000x reference)
//
#include <hip/hip_runtime.h>
#include <stdint.h>

#define B_  200
#define N0  65536

// ---------------- Threefry-2x32 (JAX-compatible, 20 rounds) ----------------
__host__ __device__ static inline void tf2x32(uint32_t k0, uint32_t k1,
                                              uint32_t x0, uint32_t x1,
                                              uint32_t& o0, uint32_t& o1) {
  const uint32_t ks2 = k0 ^ k1 ^ 0x1BD11BDAu;
  x0 += k0; x1 += k1;
#define TF_R(r) { x0 += x1; x1 = (x1 << (r)) | (x1 >> (32 - (r))); x1 ^= x0; }
  TF_R(13) TF_R(15) TF_R(26) TF_R(6)   x0 += k1;  x1 += ks2 + 1u;
  TF_R(17) TF_R(29) TF_R(16) TF_R(24)  x0 += ks2; x1 += k0  + 2u;
  TF_R(13) TF_R(15) TF_R(26) TF_R(6)   x0 += k0;  x1 += k1  + 3u;
  TF_R(17) TF_R(29) TF_R(16) TF_R(24)  x0 += k1;  x1 += ks2 + 4u;
  TF_R(13) TF_R(15) TF_R(26) TF_R(6)   x0 += ks2; x1 += k0  + 5u;
#undef TF_R
  o0 = x0; o1 = x1;
}

// ---------------- row_ptr: lower_bound over sorted dst ----------------
__global__ void build_rp_kernel(const int* __restrict__ dst, int E, int nout,
                                int* __restrict__ rp) {
  int c = blockIdx.x * blockDim.x + threadIdx.x;
  if (c > nout) return;
  int lo = 0, hi = E;
  while (lo < hi) { int mid = (lo + hi) >> 1; if (dst[mid] < c) lo = mid + 1; else hi = mid; }
  rp[c] = lo;
}

// ---------------- transpose x (200, 196608) -> xT (196608, 200) ----------------
__global__ __launch_bounds__(256) void transpose_kernel(const float* __restrict__ x,
                                                        float* __restrict__ xT) {
  __shared__ float tile[32][33];
  const int cols = N0 * 3;                 // 196608
  int j0 = blockIdx.x << 5;
  int b0 = blockIdx.y << 5;
  int tx = threadIdx.x, ty = threadIdx.y;  // (32, 8)
#pragma unroll
  for (int k = 0; k < 4; ++k) {
    int b = b0 + ty + (k << 3);
    if (b < B_) tile[ty + (k << 3)][tx] = x[(size_t)b * cols + j0 + tx];
  }
  __syncthreads();
  int b = b0 + tx;
  if (b < B_) {
#pragma unroll
    for (int k = 0; k < 4; ++k) {
      int j = j0 + ty + (k << 3);
      xT[(size_t)j * B_ + b] = tile[tx][ty + (k << 3)];
    }
  }
}

// ---------------- layer-1 pool from transposed x (coalesced in b) ----------------
__global__ __launch_bounds__(256) void pool1_t_kernel(
    const float* __restrict__ xT, const int* __restrict__ src,
    const float* __restrict__ w, const float* __restrict__ bias,
    const int* __restrict__ rp, float* __restrict__ out, int cpc) {
  int b = threadIdx.x;
  int bl = b < B_ ? b : B_ - 1;            // clamp: no OOB, no divergence
  int c0 = blockIdx.x * cpc;
  for (int cc = 0; cc < cpc; ++cc) {
    int c = c0 + cc;
    float acc = bias[c];
    int e1 = rp[c + 1];
    for (int e = rp[c]; e < e1; ++e) {
      int s = src[e];
      const float* xp = xT + (size_t)s * (3 * B_) + bl;
      float w0 = w[3 * e], w1 = w[3 * e + 1], w2 = w[3 * e + 2];
      acc = fmaf(xp[0],      w0, acc);
      acc = fmaf(xp[B_],     w1, acc);
      acc = fmaf(xp[2 * B_], w2, acc);
    }
    if (b < B_) out[(size_t)c * B_ + b] = acc;
  }
}

// ---------------- layer-1 pool, direct (fallback if ws too small) ----------------
__global__ __launch_bounds__(256) void pool1_d_kernel(
    const float* __restrict__ x, const int* __restrict__ src,
    const float* __restrict__ w, const float* __restrict__ bias,
    const int* __restrict__ rp, float* __restrict__ out, int cpc) {
  int b = threadIdx.x;
  int bl = b < B_ ? b : B_ - 1;
  int c0 = blockIdx.x * cpc;
  for (int cc = 0; cc < cpc; ++cc) {
    int c = c0 + cc;
    float acc = bias[c];
    int e1 = rp[c + 1];
    for (int e = rp[c]; e < e1; ++e) {
      int s = src[e];
      const float* xp = x + ((size_t)bl * N0 + s) * 3;
      acc = fmaf(xp[0], w[3 * e],     acc);
      acc = fmaf(xp[1], w[3 * e + 1], acc);
      acc = fmaf(xp[2], w[3 * e + 2], acc);
    }
    if (b < B_) out[(size_t)c * B_ + b] = acc;
  }
}

// ---------------- layers 2..5 pool (din=1), (c,b) layout ----------------
__global__ __launch_bounds__(256) void pooln_kernel(
    const float* __restrict__ hin, const int* __restrict__ src,
    const float* __restrict__ w, const float* __restrict__ bias,
    const int* __restrict__ rp, float* __restrict__ out, int cpc, int final_out) {
  int b = threadIdx.x;
  int bl = b < B_ ? b : B_ - 1;
  int c0 = blockIdx.x * cpc;
  for (int cc = 0; cc < cpc; ++cc) {
    int c = c0 + cc;
    float acc = bias[c];
    int e1 = rp[c + 1];
    for (int e = rp[c]; e < e1; ++e)
      acc = fmaf(hin[(size_t)src[e] * B_ + bl], w[e], acc);
    if (b < B_) {
      if (final_out) out[(size_t)b * 64 + c] = acc;      // (B, 64) row-major
      else           out[(size_t)c * B_ + b] = acc;
    }
  }
}

// ---------------- BN (training stats) + ReLU + JAX dropout ----------------
__global__ __launch_bounds__(64) void bn_act_kernel(
    const float* __restrict__ hp, const float* __restrict__ gamma,
    const float* __restrict__ beta, float* __restrict__ out,
    int nout, uint32_t k0, uint32_t k1) {
  int c = blockIdx.x;
  int lane = threadIdx.x;                  // 64 threads, one wave per channel
  const float* col = hp + (size_t)c * B_;
  float x0 = col[lane];
  float x1 = col[lane + 64];
  float x2 = col[lane + 128];
  float x3 = (lane < B_ - 192) ? col[lane + 192] : 0.f;
  float s = x0 + x1 + x2 + x3;
  float q = fmaf(x0, x0, fmaf(x1, x1, fmaf(x2, x2, x3 * x3)));
#pragma unroll
  for (int off = 32; off; off >>= 1) {
    s += __shfl_xor(s, off);
    q += __shfl_xor(q, off);
  }
  const float inv = 1.f / 200.f;
  float m    = s * inv;
  float var  = fmaf(q, inv, -m * m);       // biased variance
  float scale = gamma[c] * rsqrtf(var + 1e-5f);
  float shift = fmaf(-m, scale, beta[c]);
  uint32_t no = (uint32_t)nout;

  auto emit = [&](int b, float xv) {
    float hn = fmaxf(fmaf(xv, scale, shift), 0.f);
    uint32_t idx = (uint32_t)b * no + (uint32_t)c;   // flat index of (b, c, 0)
    uint32_t o0, o1;
    tf2x32(k0, k1, 0u, idx, o0, o1);                 // partitionable threefry
    uint32_t bits = o0 ^ o1;
    float u = __uint_as_float((bits >> 9) | 0x3f800000u) - 1.0f;
    out[(size_t)c * B_ + b] = (u < 0.9f) ? hn * (1.0f / 0.9f) : 0.0f;
  };
  emit(lane, x0);
  emit(lane + 64, x1);
  emit(lane + 128, x2);
  if (lane < B_ - 192) emit(lane + 192, x3);
}

// ---------------- KL reduction ----------------
__global__ void kl_zero_kernel(float* o) { *o = 0.f; }

__global__ __launch_bounds__(256) void kl_kernel(const float* __restrict__ w, int n,
                                                 float* __restrict__ out) {
  __shared__ float red[256];
  float s = 0.f;
  for (int i = blockIdx.x * blockDim.x + threadIdx.x; i < n;
       i += gridDim.x * blockDim.x) {
    float v = w[i];
    s += fmaf(0.5f * v, v, 999.5f);        // 0.5*(w*w-1) - (-1000)
  }
  red[threadIdx.x] = s;
  __syncthreads();
  for (int st = 128; st > 0; st >>= 1) {
    if (threadIdx.x < st) red[threadIdx.x] += red[threadIdx.x + st];
    __syncthreads();
  }
  if (threadIdx.x == 0) atomicAdd(out, red[0]);
}

// ---------------- host ----------------
extern "C" void kernel_launch(void* const* d_in, const int* in_sizes, int n_in,
                              void* d_out, int out_size, void* d_ws, size_t ws_size,
                              hipStream_t stream) {
  (void)in_sizes; (void)n_in; (void)out_size;
  const float* x = (const float*)d_in[0];
  const int*   src[5]; const int* dst[5];
  const float* w[5];   const float* bias[5];
  const float* gamma[4]; const float* beta[4];
  int idx = 1;
  for (int l = 0; l < 5; ++l) {
    src[l]  = (const int*)d_in[idx++];
    dst[l]  = (const int*)d_in[idx++];
    w[l]    = (const float*)d_in[idx++];
    bias[l] = (const float*)d_in[idx++];
    if (l < 4) { gamma[l] = (const float*)d_in[idx++]; beta[l] = (const float*)d_in[idx++]; }
  }
  static const int NOUT[5] = {16384, 4096, 1024, 256, 64};
  static const int EDG[5]  = {147456, 36864, 9216, 2304, 576};

  // dkeys = jax.random.split(key(42), 4), partitionable semantics
  uint32_t dk0[4], dk1[4];
  for (uint32_t i = 0; i < 4; ++i) tf2x32(0u, 42u, 0u, i, dk0[i], dk1[i]);

  // workspace carve
  char* ws = (char*)d_ws;
  size_t off = 0;
  auto carve = [&](size_t bytes) -> void* {
    void* p = ws + off;
    off = (off + bytes + 255) & ~(size_t)255;
    return p;
  };
  int* rp[5];
  for (int l = 0; l < 5; ++l) rp[l] = (int*)carve((size_t)(NOUT[l] + 1) * sizeof(int));
  float* bufA = (float*)carve((size_t)16384 * B_ * sizeof(float));
  float* bufB = (float*)carve((size_t)16384 * B_ * sizeof(float));
  float* xT   = (float*)carve((size_t)(N0 * 3) * B_ * sizeof(float));
  bool use_t = (off <= ws_size);

  float* kl = (float*)d_out + 12800;

  // row pointers
  for (int l = 0; l < 5; ++l)
    build_rp_kernel<<<(NOUT[l] + 1 + 255) / 256, 256, 0, stream>>>(dst[l], EDG[l], NOUT[l], rp[l]);

  // KL (independent of forward path)
  kl_zero_kernel<<<1, 1, 0, stream>>>(kl);
  for (int l = 0; l < 5; ++l) {
    int n = EDG[l] * (l == 0 ? 3 : 1);
    int g = (n + 255) / 256; if (g > 256) g = 256;
    kl_kernel<<<g, 256, 0, stream>>>(w[l], n, kl);
  }

  // layer 1
  if (use_t) {
    transpose_kernel<<<dim3((N0 * 3) / 32, (B_ + 31) / 32), dim3(32, 8), 0, stream>>>(x, xT);
    pool1_t_kernel<<<16384 / 8, 256, 0, stream>>>(xT, src[0], w[0], bias[0], rp[0], bufA, 8);
  } else {
    pool1_d_kernel<<<16384 / 8, 256, 0, stream>>>(x, src[0], w[0], bias[0], rp[0], bufA, 8);
  }
  bn_act_kernel<<<16384, 64, 0, stream>>>(bufA, gamma[0], beta[0], bufB, 16384, dk0[0], dk1[0]);
  // layer 2
  pooln_kernel<<<4096 / 4, 256, 0, stream>>>(bufB, src[1], w[1], bias[1], rp[1], bufA, 4, 0);
  bn_act_kernel<<<4096, 64, 0, stream>>>(bufA, gamma[1], beta[1], bufB, 4096, dk0[1], dk1[1]);
  // layer 3
  pooln_kernel<<<1024 / 2, 256, 0, stream>>>(bufB, src[2], w[2], bias[2], rp[2], bufA, 2, 0);
  bn_act_kernel<<<1024, 64, 0, stream>>>(bufA, gamma[2], beta[2], bufB, 1024, dk0[2], dk1[2]);
  // layer 4
  pooln_kernel<<<256, 256, 0, stream>>>(bufB, src[3], w[3], bias[3], rp[3], bufA, 1, 0);
  bn_act_kernel<<<256, 64, 0, stream>>>(bufA, gamma[3], beta[3], bufB, 256, dk0[3], dk1[3]);
  // layer 5 -> d_out (B, 64)
  pooln_kernel<<<64, 256, 0, stream>>>(bufB, src[4], w[4], bias[4], rp[4], (float*)d_out, 1, 1);
}

// Round 3
// 193.825 us; speedup vs baseline: 1.3905x; 1.3905x over previous
//
#include <hip/hip_runtime.h>
#include <stdint.h>

#define B_   200
#define N0   65536
#define COLS (N0 * 3)

// ---------------- Threefry-2x32 (JAX-compatible, 20 rounds) ----------------
__host__ __device__ static inline void tf2x32(uint32_t k0, uint32_t k1,
                                              uint32_t x0, uint32_t x1,
                                              uint32_t& o0, uint32_t& o1) {
  const uint32_t ks2 = k0 ^ k1 ^ 0x1BD11BDAu;
  x0 += k0; x1 += k1;
#define TF_R(r) { x0 += x1; x1 = (x1 << (r)) | (x1 >> (32 - (r))); x1 ^= x0; }
  TF_R(13) TF_R(15) TF_R(26) TF_R(6)   x0 += k1;  x1 += ks2 + 1u;
  TF_R(17) TF_R(29) TF_R(16) TF_R(24)  x0 += ks2; x1 += k0  + 2u;
  TF_R(13) TF_R(15) TF_R(26) TF_R(6)   x0 += k0;  x1 += k1  + 3u;
  TF_R(17) TF_R(29) TF_R(16) TF_R(24)  x0 += k1;  x1 += ks2 + 4u;
  TF_R(13) TF_R(15) TF_R(26) TF_R(6)   x0 += ks2; x1 += k0  + 5u;
#undef TF_R
  o0 = x0; o1 = x1;
}

// ---------------- all row_ptrs in one kernel (+ zero KL slot) ----------------
__global__ void build_rp_all(const int* __restrict__ dst0, const int* __restrict__ dst1,
                             const int* __restrict__ dst2, const int* __restrict__ dst3,
                             const int* __restrict__ dst4,
                             int* rp0, int* rp1, int* rp2, int* rp3, int* rp4,
                             float* kl) {
  int tid = blockIdx.x * blockDim.x + threadIdx.x;
  if (tid == 0) *kl = 0.f;
  if (tid >= 21829) return;
  const int starts[6] = {0, 16385, 20482, 21507, 21764, 21829};
  const int EDGa[5]   = {147456, 36864, 9216, 2304, 576};
  const int* dsts[5]  = {dst0, dst1, dst2, dst3, dst4};
  int* rps[5]         = {rp0, rp1, rp2, rp3, rp4};
  int l = 0;
  while (tid >= starts[l + 1]) ++l;
  int c = tid - starts[l];
  const int* dst = dsts[l];
  int lo = 0, hi = EDGa[l];
  while (lo < hi) { int mid = (lo + hi) >> 1; if (dst[mid] < c) lo = mid + 1; else hi = mid; }
  rps[l][c] = lo;
}

// ---------------- KL over all 5 weight tensors, one kernel ----------------
__global__ __launch_bounds__(256) void kl_all_kernel(
    const float* __restrict__ w0, const float* __restrict__ w1,
    const float* __restrict__ w2, const float* __restrict__ w3,
    const float* __restrict__ w4, float* __restrict__ out) {
  __shared__ float red[256];
  const float* ws[5] = {w0, w1, w2, w3, w4};
  const int    ns[5] = {442368, 36864, 9216, 2304, 576};
  int stride = gridDim.x * blockDim.x;
  int tid0 = blockIdx.x * blockDim.x + threadIdx.x;
  float s = 0.f;
#pragma unroll
  for (int l = 0; l < 5; ++l) {
    const float* w = ws[l];
    int n = ns[l];
    for (int i = tid0; i < n; i += stride) {
      float v = w[i];
      s += fmaf(0.5f * v, v, 999.5f);      // 0.5*(w*w-1) - (-1000)
    }
  }
  red[threadIdx.x] = s;
  __syncthreads();
  for (int st = 128; st > 0; st >>= 1) {
    if (threadIdx.x < st) red[threadIdx.x] += red[threadIdx.x + st];
    __syncthreads();
  }
  if (threadIdx.x == 0) atomicAdd(out, red[0]);
}

// ---------------- float4 transpose x (200, 196608) -> xT (196608, 200) ----------------
__global__ __launch_bounds__(256) void transpose4_kernel(const float* __restrict__ x,
                                                         float* __restrict__ xT) {
  __shared__ float tile[32][33];
  int tx = threadIdx.x;                    // 0..7
  int ty = threadIdx.y;                    // 0..31
  int j0 = blockIdx.x << 5;                // 6144 j-tiles
  int b0 = blockIdx.y << 5;                // 7 b-tiles
  int b = b0 + ty;
  if (b < B_) {
    float4 v = *(const float4*)(x + (size_t)b * COLS + j0 + (tx << 2));
    tile[ty][(tx << 2) + 0] = v.x;
    tile[ty][(tx << 2) + 1] = v.y;
    tile[ty][(tx << 2) + 2] = v.z;
    tile[ty][(tx << 2) + 3] = v.w;
  }
  __syncthreads();
  int bb = b0 + (tx << 2);
  if (bb + 3 < B_) {                       // B_=200 is a multiple of 4: full quads only
    float4 v;
    v.x = tile[(tx << 2) + 0][ty];
    v.y = tile[(tx << 2) + 1][ty];
    v.z = tile[(tx << 2) + 2][ty];
    v.w = tile[(tx << 2) + 3][ty];
    *(float4*)(xT + (size_t)(j0 + ty) * B_ + bb) = v;
  }
}

// ---------------- layer-1 pool + BN + ReLU + dropout (fused) ----------------
__global__ __launch_bounds__(256) void pool1_bn_kernel(
    const float* __restrict__ xT, const float* __restrict__ x,
    const int* __restrict__ src, const float* __restrict__ w,
    const float* __restrict__ bias, const int* __restrict__ rp,
    const float* __restrict__ gamma, const float* __restrict__ beta,
    float* __restrict__ out, int cpc, int use_t, uint32_t k0, uint32_t k1) {
  __shared__ float red[4][2];
  __shared__ float bcast[2];
  int b = threadIdx.x;
  int bl = b < B_ ? b : B_ - 1;
  bool valid = b < B_;
  int c0 = blockIdx.x * cpc;
  for (int cc = 0; cc < cpc; ++cc) {
    int c = c0 + cc;
    float acc = bias[c];
    int e1 = rp[c + 1];
    if (use_t) {
      for (int e = rp[c]; e < e1; ++e) {
        int s = src[e];
        const float* xp = xT + (size_t)s * (3 * B_) + bl;
        acc = fmaf(xp[0],      w[3 * e],     acc);
        acc = fmaf(xp[B_],     w[3 * e + 1], acc);
        acc = fmaf(xp[2 * B_], w[3 * e + 2], acc);
      }
    } else {
      for (int e = rp[c]; e < e1; ++e) {
        int s = src[e];
        const float* xp = x + ((size_t)bl * N0 + s) * 3;
        acc = fmaf(xp[0], w[3 * e],     acc);
        acc = fmaf(xp[1], w[3 * e + 1], acc);
        acc = fmaf(xp[2], w[3 * e + 2], acc);
      }
    }
    float sv = valid ? acc : 0.f;
    float qv = valid ? acc * acc : 0.f;
#pragma unroll
    for (int off = 32; off; off >>= 1) { sv += __shfl_xor(sv, off); qv += __shfl_xor(qv, off); }
    int wid = threadIdx.x >> 6;
    if ((threadIdx.x & 63) == 0) { red[wid][0] = sv; red[wid][1] = qv; }
    __syncthreads();
    if (threadIdx.x == 0) {
      float s2 = red[0][0] + red[1][0] + red[2][0] + red[3][0];
      float q2 = red[0][1] + red[1][1] + red[2][1] + red[3][1];
      float m   = s2 * (1.f / 200.f);
      float var = fmaf(q2, 1.f / 200.f, -m * m);
      float scale = gamma[c] * rsqrtf(var + 1e-5f);
      bcast[0] = scale;
      bcast[1] = fmaf(-m, scale, beta[c]);
    }
    __syncthreads();
    if (valid) {
      float hn = fmaxf(fmaf(acc, bcast[0], bcast[1]), 0.f);
      uint32_t idxf = (uint32_t)b * 16384u + (uint32_t)c;
      uint32_t o0, o1;
      tf2x32(k0, k1, 0u, idxf, o0, o1);
      uint32_t bits = o0 ^ o1;
      float u = __uint_as_float((bits >> 9) | 0x3f800000u) - 1.0f;
      out[(size_t)c * B_ + b] = (u < 0.9f) ? hn * (1.0f / 0.9f) : 0.0f;
    }
    __syncthreads();                       // red/bcast reused next channel
  }
}

// ---------------- layers 2..5 pool (+ optional BN/dropout), (c,b) layout ----------------
__global__ __launch_bounds__(256) void pooln_bn_kernel(
    const float* __restrict__ hin, const int* __restrict__ src,
    const float* __restrict__ w, const float* __restrict__ bias,
    const int* __restrict__ rp, const float* __restrict__ gamma,
    const float* __restrict__ beta, float* __restrict__ out,
    int cpc, int nout, int has_bn, uint32_t k0, uint32_t k1) {
  __shared__ float red[4][2];
  __shared__ float bcast[2];
  int b = threadIdx.x;
  int bl = b < B_ ? b : B_ - 1;
  bool valid = b < B_;
  int c0 = blockIdx.x * cpc;
  for (int cc = 0; cc < cpc; ++cc) {
    int c = c0 + cc;
    float acc = bias[c];
    int e1 = rp[c + 1];
    for (int e = rp[c]; e < e1; ++e)
      acc = fmaf(hin[(size_t)src[e] * B_ + bl], w[e], acc);
    if (has_bn) {
      float sv = valid ? acc : 0.f;
      float qv = valid ? acc * acc : 0.f;
#pragma unroll
      for (int off = 32; off; off >>= 1) { sv += __shfl_xor(sv, off); qv += __shfl_xor(qv, off); }
      int wid = threadIdx.x >> 6;
      if ((threadIdx.x & 63) == 0) { red[wid][0] = sv; red[wid][1] = qv; }
      __syncthreads();
      if (threadIdx.x == 0) {
        float s2 = red[0][0] + red[1][0] + red[2][0] + red[3][0];
        float q2 = red[0][1] + red[1][1] + red[2][1] + red[3][1];
        float m   = s2 * (1.f / 200.f);
        float var = fmaf(q2, 1.f / 200.f, -m * m);
        float scale = gamma[c] * rsqrtf(var + 1e-5f);
        bcast[0] = scale;
        bcast[1] = fmaf(-m, scale, beta[c]);
      }
      __syncthreads();
      if (valid) {
        float hn = fmaxf(fmaf(acc, bcast[0], bcast[1]), 0.f);
        uint32_t idxf = (uint32_t)b * (uint32_t)nout + (uint32_t)c;
        uint32_t o0, o1;
        tf2x32(k0, k1, 0u, idxf, o0, o1);
        uint32_t bits = o0 ^ o1;
        float u = __uint_as_float((bits >> 9) | 0x3f800000u) - 1.0f;
        out[(size_t)c * B_ + b] = (u < 0.9f) ? hn * (1.0f / 0.9f) : 0.0f;
      }
      __syncthreads();
    } else {
      if (valid) out[(size_t)b * 64 + c] = acc;   // final layer -> (B, 64)
    }
  }
}

// ---------------- host ----------------
extern "C" void kernel_launch(void* const* d_in, const int* in_sizes, int n_in,
                              void* d_out, int out_size, void* d_ws, size_t ws_size,
                              hipStream_t stream) {
  (void)in_sizes; (void)n_in; (void)out_size;
  const float* x = (const float*)d_in[0];
  const int*   src[5]; const int* dst[5];
  const float* w[5];   const float* bias[5];
  const float* gamma[4]; const float* beta[4];
  int idx = 1;
  for (int l = 0; l < 5; ++l) {
    src[l]  = (const int*)d_in[idx++];
    dst[l]  = (const int*)d_in[idx++];
    w[l]    = (const float*)d_in[idx++];
    bias[l] = (const float*)d_in[idx++];
    if (l < 4) { gamma[l] = (const float*)d_in[idx++]; beta[l] = (const float*)d_in[idx++]; }
  }
  static const int NOUT[5] = {16384, 4096, 1024, 256, 64};

  // dkeys = jax.random.split(key(42), 4), partitionable threefry semantics
  uint32_t dk0[4], dk1[4];
  for (uint32_t i = 0; i < 4; ++i) tf2x32(0u, 42u, 0u, i, dk0[i], dk1[i]);

  // workspace carve
  char* ws = (char*)d_ws;
  size_t off = 0;
  auto carve = [&](size_t bytes) -> void* {
    void* p = ws + off;
    off = (off + bytes + 255) & ~(size_t)255;
    return p;
  };
  int* rp[5];
  for (int l = 0; l < 5; ++l) rp[l] = (int*)carve((size_t)(NOUT[l] + 1) * sizeof(int));
  float* bufA = (float*)carve((size_t)16384 * B_ * sizeof(float));
  float* bufB = (float*)carve((size_t)16384 * B_ * sizeof(float));
  float* xT   = (float*)carve((size_t)COLS * B_ * sizeof(float));
  int use_t = (off <= ws_size) ? 1 : 0;

  float* kl = (float*)d_out + 12800;

  // 1: all row pointers + zero KL
  build_rp_all<<<(21829 + 255) / 256, 256, 0, stream>>>(
      dst[0], dst[1], dst[2], dst[3], dst[4],
      rp[0], rp[1], rp[2], rp[3], rp[4], kl);

  // 2: KL reduction (all layers)
  kl_all_kernel<<<256, 256, 0, stream>>>(w[0], w[1], w[2], w[3], w[4], kl);

  // 3: transpose
  if (use_t)
    transpose4_kernel<<<dim3(COLS / 32, 7), dim3(8, 32), 0, stream>>>(x, xT);

  // 4: layer 1 (pool + BN + ReLU + dropout)
  pool1_bn_kernel<<<16384 / 8, 256, 0, stream>>>(
      xT, x, src[0], w[0], bias[0], rp[0], gamma[0], beta[0], bufA, 8, use_t,
      dk0[0], dk1[0]);

  // 5-7: layers 2..4 (pool + BN + ReLU + dropout)
  pooln_bn_kernel<<<4096 / 4, 256, 0, stream>>>(
      bufA, src[1], w[1], bias[1], rp[1], gamma[1], beta[1], bufB, 4, 4096, 1,
      dk0[1], dk1[1]);
  pooln_bn_kernel<<<1024 / 2, 256, 0, stream>>>(
      bufB, src[2], w[2], bias[2], rp[2], gamma[2], beta[2], bufA, 2, 1024, 1,
      dk0[2], dk1[2]);
  pooln_bn_kernel<<<256, 256, 0, stream>>>(
      bufA, src[3], w[3], bias[3], rp[3], gamma[3], beta[3], bufB, 1, 256, 1,
      dk0[3], dk1[3]);

  // 8: layer 5 -> d_out (B, 64)
  pooln_bn_kernel<<<64, 256, 0, stream>>>(
      bufB, src[4], w[4], bias[4], rp[4], nullptr, nullptr, (float*)d_out, 1, 64, 0,
      0u, 0u);
}

// Round 4
// 182.501 us; speedup vs baseline: 1.4767x; 1.0620x over previous
//
#include <hip/hip_runtime.h>
#include <stdint.h>

#define B_   200
#define N0   65536
#define COLS (N0 * 3)
#define JT   32
#define TPAD 202

// ---------------- Threefry-2x32 (JAX-compatible, 20 rounds) ----------------
__host__ __device__ static inline void tf2x32(uint32_t k0, uint32_t k1,
                                              uint32_t x0, uint32_t x1,
                                              uint32_t& o0, uint32_t& o1) {
  const uint32_t ks2 = k0 ^ k1 ^ 0x1BD11BDAu;
  x0 += k0; x1 += k1;
#define TF_R(r) { x0 += x1; x1 = (x1 << (r)) | (x1 >> (32 - (r))); x1 ^= x0; }
  TF_R(13) TF_R(15) TF_R(26) TF_R(6)   x0 += k1;  x1 += ks2 + 1u;
  TF_R(17) TF_R(29) TF_R(16) TF_R(24)  x0 += ks2; x1 += k0  + 2u;
  TF_R(13) TF_R(15) TF_R(26) TF_R(6)   x0 += k0;  x1 += k1  + 3u;
  TF_R(17) TF_R(29) TF_R(16) TF_R(24)  x0 += k1;  x1 += ks2 + 4u;
  TF_R(13) TF_R(15) TF_R(26) TF_R(6)   x0 += ks2; x1 += k0  + 5u;
#undef TF_R
  o0 = x0; o1 = x1;
}

// ---------------- all row_ptrs in one kernel (+ zero KL slot) ----------------
__global__ void build_rp_all(const int* __restrict__ dst0, const int* __restrict__ dst1,
                             const int* __restrict__ dst2, const int* __restrict__ dst3,
                             const int* __restrict__ dst4,
                             int* rp0, int* rp1, int* rp2, int* rp3, int* rp4,
                             float* kl) {
  int tid = blockIdx.x * blockDim.x + threadIdx.x;
  if (tid == 0) *kl = 0.f;
  if (tid >= 21829) return;
  const int starts[6] = {0, 16385, 20482, 21507, 21764, 21829};
  const int EDGa[5]   = {147456, 36864, 9216, 2304, 576};
  const int* dsts[5]  = {dst0, dst1, dst2, dst3, dst4};
  int* rps[5]         = {rp0, rp1, rp2, rp3, rp4};
  int l = 0;
  while (tid >= starts[l + 1]) ++l;
  int c = tid - starts[l];
  const int* dst = dsts[l];
  int lo = 0, hi = EDGa[l];
  while (lo < hi) { int mid = (lo + hi) >> 1; if (dst[mid] < c) lo = mid + 1; else hi = mid; }
  rps[l][c] = lo;
}

// ---------------- KL over all 5 weight tensors, one kernel ----------------
__global__ __launch_bounds__(256) void kl_all_kernel(
    const float* __restrict__ w0, const float* __restrict__ w1,
    const float* __restrict__ w2, const float* __restrict__ w3,
    const float* __restrict__ w4, float* __restrict__ out) {
  __shared__ float red[256];
  const float* ws[5] = {w0, w1, w2, w3, w4};
  const int    ns[5] = {442368, 36864, 9216, 2304, 576};
  int stride = gridDim.x * blockDim.x;
  int tid0 = blockIdx.x * blockDim.x + threadIdx.x;
  float s = 0.f;
#pragma unroll
  for (int l = 0; l < 5; ++l) {
    const float* w = ws[l];
    int n = ns[l];
    for (int i = tid0; i < n; i += stride) {
      float v = w[i];
      s += fmaf(0.5f * v, v, 999.5f);      // 0.5*(w*w-1) - (-1000)
    }
  }
  red[threadIdx.x] = s;
  __syncthreads();
  for (int st = 128; st > 0; st >>= 1) {
    if (threadIdx.x < st) red[threadIdx.x] += red[threadIdx.x + st];
    __syncthreads();
  }
  if (threadIdx.x == 0) atomicAdd(out, red[0]);
}

// ---------------- transpose: 32 j-cols x ALL 200 b per block ----------------
// Writes 32 complete, contiguous 800B rows of xT per block -> dense streaming
// writes; x-adjacent blocks write adjacent 25.6KB chunks. 7 float4 loads in
// flight per thread on the read side.
__global__ __launch_bounds__(256) void transpose_rows_kernel(
    const float* __restrict__ x, float* __restrict__ xT) {
  __shared__ float tile[JT][TPAD];         // [j_local][b], pad 202 -> <=2-way LDS conflicts
  const int t  = threadIdx.x;
  const int j0 = blockIdx.x * JT;
  const int bl = t >> 3;                   // 0..31
  const int jj = (t & 7) << 2;             // 0,4,...,28

  float4 v[7];
#pragma unroll
  for (int p = 0; p < 7; ++p) {
    int b = bl + (p << 5);
    if (b < B_) v[p] = *(const float4*)(x + (size_t)b * COLS + j0 + jj);
  }
#pragma unroll
  for (int p = 0; p < 7; ++p) {
    int b = bl + (p << 5);
    if (b < B_) {
      tile[jj + 0][b] = v[p].x;
      tile[jj + 1][b] = v[p].y;
      tile[jj + 2][b] = v[p].z;
      tile[jj + 3][b] = v[p].w;
    }
  }
  __syncthreads();
  // 32 rows x 50 float4 = 1600 stores, full density
#pragma unroll
  for (int q = 0; q < 7; ++q) {
    int idx = t + (q << 8);
    if (idx < 1600) {
      int row = idx / 50;
      int col = (idx - row * 50) << 2;
      float4 o;
      o.x = tile[row][col + 0];
      o.y = tile[row][col + 1];
      o.z = tile[row][col + 2];
      o.w = tile[row][col + 3];
      *(float4*)(xT + (size_t)(j0 + row) * B_ + col) = o;
    }
  }
}

// ---------------- layer-1 pool + BN + ReLU + dropout (fused) ----------------
__global__ __launch_bounds__(256) void pool1_bn_kernel(
    const float* __restrict__ xT, const float* __restrict__ x,
    const int* __restrict__ src, const float* __restrict__ w,
    const float* __restrict__ bias, const int* __restrict__ rp,
    const float* __restrict__ gamma, const float* __restrict__ beta,
    float* __restrict__ out, int cpc, int use_t, uint32_t k0, uint32_t k1) {
  __shared__ float red[4][2];
  __shared__ float bcast[2];
  int b = threadIdx.x;
  int bl = b < B_ ? b : B_ - 1;
  bool valid = b < B_;
  int c0 = blockIdx.x * cpc;
  for (int cc = 0; cc < cpc; ++cc) {
    int c = c0 + cc;
    float acc = bias[c];
    int e1 = rp[c + 1];
    if (use_t) {
      for (int e = rp[c]; e < e1; ++e) {
        int s = src[e];
        const float* xp = xT + (size_t)s * (3 * B_) + bl;
        acc = fmaf(xp[0],      w[3 * e],     acc);
        acc = fmaf(xp[B_],     w[3 * e + 1], acc);
        acc = fmaf(xp[2 * B_], w[3 * e + 2], acc);
      }
    } else {
      for (int e = rp[c]; e < e1; ++e) {
        int s = src[e];
        const float* xp = x + ((size_t)bl * N0 + s) * 3;
        acc = fmaf(xp[0], w[3 * e],     acc);
        acc = fmaf(xp[1], w[3 * e + 1], acc);
        acc = fmaf(xp[2], w[3 * e + 2], acc);
      }
    }
    float sv = valid ? acc : 0.f;
    float qv = valid ? acc * acc : 0.f;
#pragma unroll
    for (int off = 32; off; off >>= 1) { sv += __shfl_xor(sv, off); qv += __shfl_xor(qv, off); }
    int wid = threadIdx.x >> 6;
    if ((threadIdx.x & 63) == 0) { red[wid][0] = sv; red[wid][1] = qv; }
    __syncthreads();
    if (threadIdx.x == 0) {
      float s2 = red[0][0] + red[1][0] + red[2][0] + red[3][0];
      float q2 = red[0][1] + red[1][1] + red[2][1] + red[3][1];
      float m   = s2 * (1.f / 200.f);
      float var = fmaf(q2, 1.f / 200.f, -m * m);
      float scale = gamma[c] * rsqrtf(var + 1e-5f);
      bcast[0] = scale;
      bcast[1] = fmaf(-m, scale, beta[c]);
    }
    __syncthreads();
    if (valid) {
      float hn = fmaxf(fmaf(acc, bcast[0], bcast[1]), 0.f);
      uint32_t idxf = (uint32_t)b * 16384u + (uint32_t)c;
      uint32_t o0, o1;
      tf2x32(k0, k1, 0u, idxf, o0, o1);
      uint32_t bits = o0 ^ o1;
      float u = __uint_as_float((bits >> 9) | 0x3f800000u) - 1.0f;
      out[(size_t)c * B_ + b] = (u < 0.9f) ? hn * (1.0f / 0.9f) : 0.0f;
    }
    __syncthreads();                       // red/bcast reused next channel
  }
}

// ---------------- layers 2..5 pool (+ optional BN/dropout), (c,b) layout ----------------
__global__ __launch_bounds__(256) void pooln_bn_kernel(
    const float* __restrict__ hin, const int* __restrict__ src,
    const float* __restrict__ w, const float* __restrict__ bias,
    const int* __restrict__ rp, const float* __restrict__ gamma,
    const float* __restrict__ beta, float* __restrict__ out,
    int cpc, int nout, int has_bn, uint32_t k0, uint32_t k1) {
  __shared__ float red[4][2];
  __shared__ float bcast[2];
  int b = threadIdx.x;
  int bl = b < B_ ? b : B_ - 1;
  bool valid = b < B_;
  int c0 = blockIdx.x * cpc;
  for (int cc = 0; cc < cpc; ++cc) {
    int c = c0 + cc;
    float acc = bias[c];
    int e1 = rp[c + 1];
    for (int e = rp[c]; e < e1; ++e)
      acc = fmaf(hin[(size_t)src[e] * B_ + bl], w[e], acc);
    if (has_bn) {
      float sv = valid ? acc : 0.f;
      float qv = valid ? acc * acc : 0.f;
#pragma unroll
      for (int off = 32; off; off >>= 1) { sv += __shfl_xor(sv, off); qv += __shfl_xor(qv, off); }
      int wid = threadIdx.x >> 6;
      if ((threadIdx.x & 63) == 0) { red[wid][0] = sv; red[wid][1] = qv; }
      __syncthreads();
      if (threadIdx.x == 0) {
        float s2 = red[0][0] + red[1][0] + red[2][0] + red[3][0];
        float q2 = red[0][1] + red[1][1] + red[2][1] + red[3][1];
        float m   = s2 * (1.f / 200.f);
        float var = fmaf(q2, 1.f / 200.f, -m * m);
        float scale = gamma[c] * rsqrtf(var + 1e-5f);
        bcast[0] = scale;
        bcast[1] = fmaf(-m, scale, beta[c]);
      }
      __syncthreads();
      if (valid) {
        float hn = fmaxf(fmaf(acc, bcast[0], bcast[1]), 0.f);
        uint32_t idxf = (uint32_t)b * (uint32_t)nout + (uint32_t)c;
        uint32_t o0, o1;
        tf2x32(k0, k1, 0u, idxf, o0, o1);
        uint32_t bits = o0 ^ o1;
        float u = __uint_as_float((bits >> 9) | 0x3f800000u) - 1.0f;
        out[(size_t)c * B_ + b] = (u < 0.9f) ? hn * (1.0f / 0.9f) : 0.0f;
      }
      __syncthreads();
    } else {
      if (valid) out[(size_t)b * 64 + c] = acc;   // final layer -> (B, 64)
    }
  }
}

// ---------------- host ----------------
extern "C" void kernel_launch(void* const* d_in, const int* in_sizes, int n_in,
                              void* d_out, int out_size, void* d_ws, size_t ws_size,
                              hipStream_t stream) {
  (void)in_sizes; (void)n_in; (void)out_size;
  const float* x = (const float*)d_in[0];
  const int*   src[5]; const int* dst[5];
  const float* w[5];   const float* bias[5];
  const float* gamma[4]; const float* beta[4];
  int idx = 1;
  for (int l = 0; l < 5; ++l) {
    src[l]  = (const int*)d_in[idx++];
    dst[l]  = (const int*)d_in[idx++];
    w[l]    = (const float*)d_in[idx++];
    bias[l] = (const float*)d_in[idx++];
    if (l < 4) { gamma[l] = (const float*)d_in[idx++]; beta[l] = (const float*)d_in[idx++]; }
  }
  static const int NOUT[5] = {16384, 4096, 1024, 256, 64};

  // dkeys = jax.random.split(key(42), 4), partitionable threefry semantics
  uint32_t dk0[4], dk1[4];
  for (uint32_t i = 0; i < 4; ++i) tf2x32(0u, 42u, 0u, i, dk0[i], dk1[i]);

  // workspace carve
  char* ws = (char*)d_ws;
  size_t off = 0;
  auto carve = [&](size_t bytes) -> void* {
    void* p = ws + off;
    off = (off + bytes + 255) & ~(size_t)255;
    return p;
  };
  int* rp[5];
  for (int l = 0; l < 5; ++l) rp[l] = (int*)carve((size_t)(NOUT[l] + 1) * sizeof(int));
  float* bufA = (float*)carve((size_t)16384 * B_ * sizeof(float));
  float* bufB = (float*)carve((size_t)16384 * B_ * sizeof(float));
  float* xT   = (float*)carve((size_t)COLS * B_ * sizeof(float));
  int use_t = (off <= ws_size) ? 1 : 0;

  float* kl = (float*)d_out + 12800;

  // 1: all row pointers + zero KL
  build_rp_all<<<(21829 + 255) / 256, 256, 0, stream>>>(
      dst[0], dst[1], dst[2], dst[3], dst[4],
      rp[0], rp[1], rp[2], rp[3], rp[4], kl);

  // 2: KL reduction (all layers)
  kl_all_kernel<<<256, 256, 0, stream>>>(w[0], w[1], w[2], w[3], w[4], kl);

  // 3: transpose (full-row tiles)
  if (use_t)
    transpose_rows_kernel<<<COLS / JT, 256, 0, stream>>>(x, xT);

  // 4: layer 1 (pool + BN + ReLU + dropout)
  pool1_bn_kernel<<<16384 / 8, 256, 0, stream>>>(
      xT, x, src[0], w[0], bias[0], rp[0], gamma[0], beta[0], bufA, 8, use_t,
      dk0[0], dk1[0]);

  // 5-7: layers 2..4 (pool + BN + ReLU + dropout)
  pooln_bn_kernel<<<4096 / 4, 256, 0, stream>>>(
      bufA, src[1], w[1], bias[1], rp[1], gamma[1], beta[1], bufB, 4, 4096, 1,
      dk0[1], dk1[1]);
  pooln_bn_kernel<<<1024 / 2, 256, 0, stream>>>(
      bufB, src[2], w[2], bias[2], rp[2], gamma[2], beta[2], bufA, 2, 1024, 1,
      dk0[2], dk1[2]);
  pooln_bn_kernel<<<256, 256, 0, stream>>>(
      bufA, src[3], w[3], bias[3], rp[3], gamma[3], beta[3], bufB, 1, 256, 1,
      dk0[3], dk1[3]);

  // 8: layer 5 -> d_out (B, 64)
  pooln_bn_kernel<<<64, 256, 0, stream>>>(
      bufB, src[4], w[4], bias[4], rp[4], nullptr, nullptr, (float*)d_out, 1, 64, 0,
      0u, 0u);
}